// Round 4
// baseline (329.141 us; speedup 1.0000x reference)
//
#include <hip/hip_runtime.h>
#include <math.h>

// ---------------- problem constants ----------------
#define TASKS 64
#define NB    4096
#define TDI   512     // token dim (K of GEMM1)
#define HDI   256     // hidden dim
#define VDI   484     // visual dim (padded to 512; row 484 = wc = W2^T.c fused dot column)

// ---------------- ws layout (bytes): frag-order (pre-swizzled) fp16 arrays ----------------
// tf : [64 rb][16 ks][4 rt][4 q][16 l15][8h]  f16  (4 MB)   unit strides: l15=1,q=16,rt=64,ks=256,rb=4096
// w1 : [64 t][4 w][16 ks][4 ct][4 q][16 l15][8h]   (16 MB)  strides: q=16,ct=64,ks=256,w=4096,t=16384
// w2 : [64 t][2 p][4 w][8 ks][4 ct][4 q][16 l15][8h] (16MB)  strides: q=16,ct=64,ks=256,w=2048,p=8192,t=16384
#define WS_TF   ((size_t)0)
#define WS_W1   ((size_t)4194304)
#define WS_W2   ((size_t)20971520)
#define WS_CN   ((size_t)37748736)                // 64 f32 centroid norms
#define WS_BC   ((size_t)37748992)                // 64 f32 b2.c
#define WS_ACC  ((size_t)37749248)                // 64 f32 distance accumulators
#define WS_WCP  ((size_t)37749504)                // [4 q][64 t][256 h] f32 wc partials (256 KB)

// ---------------- LDS layout (bytes): 37376 total ----------------
// HP: [8 ks][4 rt][4 q][16 l15][8h] f16 = 32768  (frag-order for GEMM2 A)
#define LDS_HP 0
#define LDS_B2 32768      // 512 f32: b2 (col 484 = b2.c, 485.. = 0)
#define LDS_R0 34816      // 256 f32: [4w][64m]
#define LDS_R1 35840      // 256 f32
#define LDS_MU 36864      // 64 f32
#define LDS_RS 37120      // 64 f32
#define SMEM_BYTES 37376

typedef _Float16 half8 __attribute__((ext_vector_type(8)));
typedef float    f32x4 __attribute__((ext_vector_type(4)));

#define MFMA16(a, b, c) __builtin_amdgcn_mfma_f32_16x16x32_f16((a), (b), (c), 0, 0, 0)

__device__ __forceinline__ half8 cvt8f(float4 v0, float4 v1) {
  half8 r;
  r[0]=(_Float16)v0.x; r[1]=(_Float16)v0.y; r[2]=(_Float16)v0.z; r[3]=(_Float16)v0.w;
  r[4]=(_Float16)v1.x; r[5]=(_Float16)v1.y; r[6]=(_Float16)v1.z; r[7]=(_Float16)v1.w;
  return r;
}

// Exact-GELU via Abramowitz-Stegun 7.1.26 erf (|err| <= 1.5e-7), ~14 VALU ops, branch-free.
__device__ __forceinline__ float gelu_exact(float x) {
  float az = fabsf(x) * 0.70710678118654752f;          // |x|/sqrt(2)
  float d  = fmaf(0.3275911f, az, 1.0f);
  float t; asm("v_rcp_f32 %0, %1" : "=v"(t) : "v"(d));
  float p  = fmaf(t, 1.061405429f, -1.453152027f);
  p = fmaf(t, p, 1.421413741f);
  p = fmaf(t, p, -0.284496736f);
  p = fmaf(t, p, 0.254829592f);
  p = p * t;
  float m = az * az * -1.4426950408889634f;            // -z^2 * log2(e)
  float e; asm("v_exp_f32 %0, %1" : "=v"(e) : "v"(m)); // 2^m = exp(-z^2)
  float er = fmaf(-p, e, 1.0f);                        // erf(|z|)
  er = copysignf(er, x);
  float hx = 0.5f * x;
  return fmaf(hx, er, hx);                             // 0.5*x*(1+erf)
}

// ================= prepass: fp32 -> frag-order fp16 via LDS tile transpose =================
// Blocks: [0,256) wc partials (4 per task, latency-parallel, FIRST so loads overlap copies)
//         [256,512) tf | [512,1536) W1 | [1536,2560) W2.
extern "C" __global__ void __launch_bounds__(256, 8)
prep_all(const float* __restrict__ t_feat,
         const float* __restrict__ W1,
         const float* __restrict__ W2,
         const float* __restrict__ cent,
         _Float16* __restrict__ tf,
         _Float16* __restrict__ w1,
         _Float16* __restrict__ w2,
         float* __restrict__ wcp) {
  __shared__ __align__(16) char pbuf[17408];           // 64 rows x 272B (128 f16 + 16B pad)
  const int bid = blockIdx.x, tid = threadIdx.x;

  if (bid < 256) {                         // wc partial: t = bid>>2, quarter q = bid&3
    int t = bid >> 2, q = bid & 3;
    int h = tid;
    int vs = q * 121;                      // 484 = 4*121
    const float* wp = W2 + ((size_t)t * VDI + vs) * HDI + h;
    const float* cp = cent + (size_t)t * VDI + vs;
    float s = 0.f;
    int v = 0;
    #pragma unroll 1
    for (; v + 8 <= 121; v += 8) {         // 8 loads in flight per round
      float x0 = wp[0 * 256], x1 = wp[1 * 256], x2 = wp[2 * 256], x3 = wp[3 * 256];
      float x4 = wp[4 * 256], x5 = wp[5 * 256], x6 = wp[6 * 256], x7 = wp[7 * 256];
      s = fmaf(x0, cp[v + 0], s); s = fmaf(x1, cp[v + 1], s);
      s = fmaf(x2, cp[v + 2], s); s = fmaf(x3, cp[v + 3], s);
      s = fmaf(x4, cp[v + 4], s); s = fmaf(x5, cp[v + 5], s);
      s = fmaf(x6, cp[v + 6], s); s = fmaf(x7, cp[v + 7], s);
      wp += 8 * 256;
    }
    s = fmaf(wp[0], cp[v], s);             // tail (121 = 15*8 + 1)
    wcp[((size_t)q * 64 + t) * 256 + h] = s;
    return;
  }

  const float* src;        // f32 base (pre-offset by kq*128 within row)
  half8* dst;              // output chunk base (1024 contiguous 16B units)
  int w2vdBase = -1;       // >=0: W2 tile, rows vd = w2vdBase + row_local

  if (bid < 512) {                         // tf: rb, kq
    int g = bid - 256;
    int rb = g >> 2, kq = g & 3;
    src = t_feat + (size_t)rb * 64 * 512 + kq * 128;
    dst = (half8*)tf + ((size_t)rb * 4096 + kq * 1024);
  } else if (bid < 1536) {                 // W1
    int g = bid - 512;
    int t = g >> 4, w_ = (g >> 2) & 3, kq = g & 3;
    src = W1 + ((size_t)t * 256 + w_ * 64) * 512 + kq * 128;
    dst = (half8*)w1 + ((size_t)t * 16384 + w_ * 4096 + kq * 1024);
  } else {                                 // W2
    int g = bid - 1536;
    int t = g >> 4, sub = g & 15;
    int p = sub >> 3, w_ = (sub >> 1) & 3, kq = sub & 1;
    src = W2 + (size_t)t * 484 * 256 + kq * 128;
    w2vdBase = p * 256 + w_ * 64;
    dst = (half8*)w2 + ((size_t)t * 16384 + p * 8192 + w_ * 2048 + kq * 1024);
  }

  // ---- stage 1: coalesced f32 read -> f16 LDS tile ----
  const int srcStride = (w2vdBase < 0) ? 512 : 256;    // tf/W1 rows 512 f32, W2 rows 256
  ushort* lds = (ushort*)pbuf;
  #pragma unroll
  for (int j = 0; j < 8; ++j) {
    int f = j * 256 + tid;                 // float4 index in [0, 2048)
    int row = f >> 5, kc = f & 31;         // 32 float4 per row
    float4 v0 = make_float4(0.f, 0.f, 0.f, 0.f);
    if (w2vdBase < 0) {
      v0 = ((const float4*)(src + (size_t)row * srcStride))[kc];
    } else {
      int vd = w2vdBase + row;
      if (vd < VDI) v0 = ((const float4*)(src + (size_t)vd * 256))[kc];
    }
    _Float16 h4[4] = {(_Float16)v0.x, (_Float16)v0.y, (_Float16)v0.z, (_Float16)v0.w};
    *(ushort4*)(&lds[row * 136 + kc * 4]) = *(const ushort4*)h4;
  }
  __syncthreads();

  // ---- stage 2: LDS -> output-linear units, fully coalesced 16B stores ----
  // (row 484 = wc gets zeros here; prep_fin overwrites it afterwards)
  #pragma unroll
  for (int j = 0; j < 4; ++j) {
    int u = j * 256 + tid;                 // unit index in [0, 1024)
    int ksl = u >> 8, rg = (u >> 6) & 3, q = (u >> 4) & 3, l15 = u & 15;
    int row = rg * 16 + l15, k8l = ksl * 4 + q;
    dst[u] = *(const half8*)(pbuf + row * 272 + k8l * 16);
  }
}

// ===== prep_fin: sum wc partials -> f16 row 484; cnorm, b2.c, accum=0 (64 blocks) =====
extern "C" __global__ void prep_fin(const float* __restrict__ wcp,
                                    const float* __restrict__ b2,
                                    const float* __restrict__ cent,
                                    _Float16* __restrict__ w2,
                                    float* __restrict__ cnorm,
                                    float* __restrict__ bc,
                                    float* __restrict__ accum) {
  __shared__ float redc[256], redb[256];
  const int t = blockIdx.x, h = threadIdx.x;
  float wc = wcp[((size_t)0 * 64 + t) * 256 + h] + wcp[((size_t)1 * 64 + t) * 256 + h]
           + wcp[((size_t)2 * 64 + t) * 256 + h] + wcp[((size_t)3 * 64 + t) * 256 + h];
  // vd=484 -> p=1, w=3, ct=2, l15=4 ; ks = h>>5, q=(h>>3)&3, within-unit h&7
  int ks = h >> 5, q = (h >> 3) & 3;
  size_t o = (size_t)t * 16384 + 8192 + 3 * 2048 + ks * 256 + 2 * 64 + q * 16 + 4;
  w2[o * 8 + (h & 7)] = (_Float16)wc;

  float c2 = 0.f, b2c = 0.f;
  for (int v = h; v < VDI; v += 256) {
    float c = cent[(size_t)t * VDI + v];
    c2 += c * c;
    b2c += b2[(size_t)t * VDI + v] * c;
  }
  redc[h] = c2; redb[h] = b2c;
  __syncthreads();
  if (h < 64) {
    c2  = redc[h] + redc[h + 64] + redc[h + 128] + redc[h + 192];
    b2c = redb[h] + redb[h + 64] + redb[h + 128] + redb[h + 192];
    #pragma unroll
    for (int off = 32; off; off >>= 1) { c2 += __shfl_xor(c2, off); b2c += __shfl_xor(b2c, off); }
    if (h == 0) { cnorm[t] = sqrtf(c2); bc[t] = b2c; accum[t] = 0.f; }
  }
}

// ============ fused main: 256 thr / 4 waves / 64x64 per wave, 4 blocks/CU ============
// Spill-free phases; all per-task vector loads in barrier shadows; phase-3 B frags
// prefetched across phase boundaries (pass0 during phase-2 normalize, pass1 during
// pass-0 epilogue). s_setprio(1) around MFMA clusters (4 de-phased blocks/CU).

#define STEP_RELOAD(A, ACC, PB) do {                                           \
  __builtin_amdgcn_s_setprio(1);                                               \
  _Pragma("unroll") for (int ct_ = 0; ct_ < 4; ++ct_) {                        \
    ACC[0][ct_] = MFMA16(A[0], b[ct_], ACC[0][ct_]);                           \
    ACC[1][ct_] = MFMA16(A[1], b[ct_], ACC[1][ct_]);                           \
    ACC[2][ct_] = MFMA16(A[2], b[ct_], ACC[2][ct_]);                           \
    ACC[3][ct_] = MFMA16(A[3], b[ct_], ACC[3][ct_]);                           \
    b[ct_] = (PB)[ct_ * 64];                                                   \
  }                                                                            \
  __builtin_amdgcn_s_setprio(0);                                               \
} while (0)

#define STEP_LAST(A, ACC) do {                                                 \
  __builtin_amdgcn_s_setprio(1);                                               \
  _Pragma("unroll") for (int ct_ = 0; ct_ < 4; ++ct_) {                        \
    ACC[0][ct_] = MFMA16(A[0], b[ct_], ACC[0][ct_]);                           \
    ACC[1][ct_] = MFMA16(A[1], b[ct_], ACC[1][ct_]);                           \
    ACC[2][ct_] = MFMA16(A[2], b[ct_], ACC[2][ct_]);                           \
    ACC[3][ct_] = MFMA16(A[3], b[ct_], ACC[3][ct_]);                           \
  }                                                                            \
  __builtin_amdgcn_s_setprio(0);                                               \
} while (0)

#define LD_A4(D, P) do { D[0] = (P)[0]; D[1] = (P)[64]; D[2] = (P)[128]; D[3] = (P)[192]; } while (0)

// Phase-3 step: 16 MFMA; B (global) reloaded per-ct (12-MFMA gap); A (LDS) single-buffered,
// reloaded interleaved with the ct=3 MFMAs.
#define P3_STEP(ACC, HN) do {                                                  \
  __builtin_amdgcn_s_setprio(1);                                               \
  ACC[0][0]=MFMA16(a0[0],b[0],ACC[0][0]); ACC[1][0]=MFMA16(a0[1],b[0],ACC[1][0]); \
  ACC[2][0]=MFMA16(a0[2],b[0],ACC[2][0]); ACC[3][0]=MFMA16(a0[3],b[0],ACC[3][0]); \
  b[0]=pc[0];                                                                  \
  ACC[0][1]=MFMA16(a0[0],b[1],ACC[0][1]); ACC[1][1]=MFMA16(a0[1],b[1],ACC[1][1]); \
  ACC[2][1]=MFMA16(a0[2],b[1],ACC[2][1]); ACC[3][1]=MFMA16(a0[3],b[1],ACC[3][1]); \
  b[1]=pc[64];                                                                 \
  ACC[0][2]=MFMA16(a0[0],b[2],ACC[0][2]); ACC[1][2]=MFMA16(a0[1],b[2],ACC[1][2]); \
  ACC[2][2]=MFMA16(a0[2],b[2],ACC[2][2]); ACC[3][2]=MFMA16(a0[3],b[2],ACC[3][2]); \
  b[2]=pc[128];                                                                \
  ACC[0][3]=MFMA16(a0[0],b[3],ACC[0][3]); a0[0]=*(const half8*)(HN);           \
  ACC[1][3]=MFMA16(a0[1],b[3],ACC[1][3]); a0[1]=*(const half8*)((HN)+1024);    \
  ACC[2][3]=MFMA16(a0[2],b[3],ACC[2][3]); a0[2]=*(const half8*)((HN)+2048);    \
  ACC[3][3]=MFMA16(a0[3],b[3],ACC[3][3]); a0[3]=*(const half8*)((HN)+3072);    \
  b[3]=pc[192]; pc+=256;                                                       \
  __builtin_amdgcn_s_setprio(0);                                               \
} while (0)

extern "C" __global__ void __launch_bounds__(256, 4)
router_main(const half8* __restrict__ tfv,
            const half8* __restrict__ w1v,
            const half8* __restrict__ w2v,
            const float* __restrict__ b1,
            const float* __restrict__ gamma,
            const float* __restrict__ beta,
            const float* __restrict__ b2,
            const float* __restrict__ bc,
            const float* __restrict__ cnorm,
            float* __restrict__ accum) {
  __shared__ __align__(16) char smem[SMEM_BYTES];

  const int tid = threadIdx.x;
  const int bx  = blockIdx.x;
  // XCD swizzle: each XCD (bx&7) works one task at a time -> task weights L2-resident.
  const int t  = ((bx & 7) << 3) | (bx >> 9);
  const int rb = (bx >> 3) & 63;

  const int lane = tid & 63;
  const int w    = tid >> 6;       // wave id 0..3
  const int quad = lane >> 4;
  const int l15  = lane & 15;

  f32x4 zero4 = {0.f, 0.f, 0.f, 0.f};
  f32x4 acc[4][4];
  #pragma unroll
  for (int rt = 0; rt < 4; ++rt)
    #pragma unroll
    for (int ct = 0; ct < 4; ++ct) acc[rt][ct] = zero4;

  half8 a0[4], a1[4], b[4];

  // ================= Phase 1: GEMM1 (K=512), barrier-free, frags direct from L2 =================
  {
    const half8* pa = tfv + ((size_t)rb * 4096 + quad * 16 + l15);
    const half8* pb = w1v + ((size_t)t * 16384 + w * 4096 + quad * 16 + l15);
    LD_A4(a0, pa);                                     // ks0
    b[0] = pb[0]; b[1] = pb[64]; b[2] = pb[128]; b[3] = pb[192];   // ks0
    a1[0] = pa[256]; a1[1] = pa[320]; a1[2] = pa[384]; a1[3] = pa[448]; // ks1
    pa += 512;            // next A load = ks2
    pb += 256;            // next B load = ks1
    #pragma unroll 1
    for (int ks = 0; ks < 14; ks += 2) {
      STEP_RELOAD(a0, acc, pb); pb += 256;   // uses ks, b <- ks+1
      LD_A4(a0, pa);            pa += 256;   // a0 <- ks+2
      STEP_RELOAD(a1, acc, pb); pb += 256;   // uses ks+1, b <- ks+2
      LD_A4(a1, pa);            pa += 256;   // a1 <- ks+3
    }
    STEP_RELOAD(a0, acc, pb);                // ks14, b <- ks15
    STEP_LAST(a1, acc);                      // ks15
  }

  // ================= Phase 2: +b1, LayerNorm, exact GELU -> H' (frag-order f16) in LDS =================
  float b1v[4];
  #pragma unroll
  for (int ct = 0; ct < 4; ++ct)
    b1v[ct] = b1[t * HDI + w * 64 + ct * 16 + l15];
  {
    float* red0 = (float*)(smem + LDS_R0);
    float* red1 = (float*)(smem + LDS_R1);
    #pragma unroll
    for (int rt = 0; rt < 4; ++rt)
      #pragma unroll
      for (int r = 0; r < 4; ++r) {
        float sv = 0.f, qv = 0.f;
        #pragma unroll
        for (int ct = 0; ct < 4; ++ct) {
          float v = acc[rt][ct][r] + b1v[ct];
          acc[rt][ct][r] = v;
          sv += v; qv += v * v;
        }
        sv += __shfl_xor(sv, 1); qv += __shfl_xor(qv, 1);
        sv += __shfl_xor(sv, 2); qv += __shfl_xor(qv, 2);
        sv += __shfl_xor(sv, 4); qv += __shfl_xor(qv, 4);
        sv += __shfl_xor(sv, 8); qv += __shfl_xor(qv, 8);
        if (l15 == 0) {
          int m = rt * 16 + quad * 4 + r;
          red0[w * 64 + m] = sv;
          red1[w * 64 + m] = qv;
        }
      }
    __syncthreads();
    if (tid < 64) {
      float s = red0[tid] + red0[64 + tid] + red0[128 + tid] + red0[192 + tid];
      float q = red1[tid] + red1[64 + tid] + red1[128 + tid] + red1[192 + tid];
      float mu = s * (1.f / HDI);
      float var = q * (1.f / HDI) - mu * mu;
      ((float*)(smem + LDS_MU))[tid] = mu;
      ((float*)(smem + LDS_RS))[tid] = rsqrtf(var + 1e-5f);
    }
    // barrier-shadow loads: gamma/beta + b2 LDS staging overlap the stats barrier
    float gvv[4], bevv[4];
    #pragma unroll
    for (int ct = 0; ct < 4; ++ct) {
      gvv[ct]  = gamma[t * HDI + w * 64 + ct * 16 + l15];
      bevv[ct] = beta [t * HDI + w * 64 + ct * 16 + l15];
    }
    {
      float* b2s = (float*)(smem + LDS_B2);
      int i0 = tid;
      b2s[i0] = (i0 < VDI) ? b2[(size_t)t * VDI + i0] : 0.f;
      int i1 = tid + 256;
      float v = 0.f;
      if (i1 < VDI) v = b2[(size_t)t * VDI + i1];
      else if (i1 == VDI) v = bc[t];
      b2s[i1] = v;
    }
    __syncthreads();
    // prefetch phase-3 pass-0 ks0 B frags under the normalize VALU shadow
    {
      const half8* p0 = w2v + ((size_t)t * 16384 + w * 2048 + quad * 16 + l15);
      b[0] = p0[0]; b[1] = p0[64]; b[2] = p0[128]; b[3] = p0[192];
    }
    const float* mus = (const float*)(smem + LDS_MU);
    const float* rss = (const float*)(smem + LDS_RS);
    #pragma unroll
    for (int rt = 0; rt < 4; ++rt) {
      float m4[4], s4[4];
      #pragma unroll
      for (int r = 0; r < 4; ++r) {
        int m = rt * 16 + quad * 4 + r;
        m4[r] = mus[m]; s4[r] = rss[m];
      }
      #pragma unroll
      for (int ct = 0; ct < 4; ++ct) {
        int col = w * 64 + ct * 16 + l15;
        // HP[ks2][rt][quad2][m&15][col&7]: ks2=col>>5, quad2=(col>>3)&3, m&15=quad*4+r
        int base = (((col >> 5) * 4 + rt) * 4 + ((col >> 3) & 3)) * 256
                 + quad * 64 + (l15 & 7) * 2;
        #pragma unroll
        for (int r = 0; r < 4; ++r) {
          float x = (acc[rt][ct][r] - m4[r]) * s4[r];
          x = x * gvv[ct] + bevv[ct];
          *(_Float16*)(smem + LDS_HP + base + r * 16) = (_Float16)gelu_exact(x);
        }
      }
    }
    __syncthreads();
  }

  // ================= Phase 3: GEMM2 (2 N-passes of 256, incl. fused wc dot column) =================
  {
    const float* b2s = (const float*)(smem + LDS_B2);
    float* red0 = (float*)(smem + LDS_R0);
    float* red1 = (float*)(smem + LDS_R1);
    const char* ha = smem + LDS_HP + quad * 256 + l15 * 16;
    const half8* pcb = w2v + ((size_t)t * 16384 + w * 2048 + quad * 16 + l15);

    #pragma unroll 1
    for (int pass = 0; pass < 2; ++pass) {
      const half8* pc = pcb + pass * 8192 + 256;       // ks0 B already in b[]
      f32x4 acc2[4][4];
      #pragma unroll
      for (int rt = 0; rt < 4; ++rt)
        #pragma unroll
        for (int ct = 0; ct < 4; ++ct) acc2[rt][ct] = zero4;

      a0[0] = *(const half8*)(ha);        a0[1] = *(const half8*)(ha + 1024);
      a0[2] = *(const half8*)(ha + 2048); a0[3] = *(const half8*)(ha + 3072);
      #pragma unroll 1
      for (int ks = 0; ks < 7; ++ks) {
        P3_STEP(acc2, ha + (ks + 1) * 4096);
      }
      STEP_LAST(a0, acc2);                 // ks7
      if (pass == 0) {                     // prefetch pass-1 ks0 B under the epilogue
        const half8* pn = pcb + 8192;
        b[0] = pn[0]; b[1] = pn[64]; b[2] = pn[128]; b[3] = pn[192];
      }

      // epilogue: per-row |v|^2 (cols<484) and dot (col 484 = wc column + b2.c)
      #pragma unroll
      for (int rt = 0; rt < 4; ++rt)
        #pragma unroll
        for (int r = 0; r < 4; ++r) {
          float ssq = 0.f, dtv = 0.f;
          #pragma unroll
          for (int ct = 0; ct < 4; ++ct) {
            int vcol = pass * 256 + w * 64 + ct * 16 + l15;
            float val = acc2[rt][ct][r] + b2s[vcol];
            ssq += (vcol < VDI) ? val * val : 0.f;
            dtv += (vcol == VDI) ? val : 0.f;
          }
          ssq += __shfl_xor(ssq, 1); dtv += __shfl_xor(dtv, 1);
          ssq += __shfl_xor(ssq, 2); dtv += __shfl_xor(dtv, 2);
          ssq += __shfl_xor(ssq, 4); dtv += __shfl_xor(dtv, 4);
          ssq += __shfl_xor(ssq, 8); dtv += __shfl_xor(dtv, 8);
          if (l15 == 0) {
            int m = rt * 16 + quad * 4 + r;
            if (pass == 0) {
              red0[w * 64 + m] = ssq;
            } else {
              red0[w * 64 + m] += ssq;
              red1[w * 64 + m] = dtv;
            }
          }
        }
    }

    __syncthreads();
    if (tid < 64) {
      float ss  = red0[tid] + red0[64 + tid] + red0[128 + tid] + red0[192 + tid];
      float dot = red1[tid] + red1[64 + tid] + red1[128 + tid] + red1[192 + tid];
      float cn = fmaxf(cnorm[t], 1e-8f);
      float vn = fmaxf(sqrtf(ss), 1e-8f);
      float part = 1.0f - dot / (vn * cn);
      part += __shfl_down(part, 32);
      part += __shfl_down(part, 16);
      part += __shfl_down(part, 8);
      part += __shfl_down(part, 4);
      part += __shfl_down(part, 2);
      part += __shfl_down(part, 1);
      if (tid == 0) atomicAdd(accum + t, part);
    }
  }
}

// ================= finalize: mean, argmin =================
extern "C" __global__ void finalize_k(const float* __restrict__ accum, float* __restrict__ out) {
  int t = threadIdx.x;                               // <<<1, 64>>>
  float d = accum[t] * (1.0f / (float)NB);
  out[t] = d;
  float bd = d; int bi = t;
  #pragma unroll
  for (int off = 32; off; off >>= 1) {
    float od = __shfl_xor(bd, off);
    int   oi = __shfl_xor(bi, off);
    if (od < bd || (od == bd && oi < bi)) { bd = od; bi = oi; }   // first-min tie-break
  }
  if (t == 0) out[64] = (float)bi;
}

extern "C" void kernel_launch(void* const* d_in, const int* in_sizes, int n_in,
                              void* d_out, int out_size, void* d_ws, size_t ws_size,
                              hipStream_t stream) {
  const float* t_feat = (const float*)d_in[0];
  const float* W1     = (const float*)d_in[1];
  const float* b1     = (const float*)d_in[2];
  const float* gamma  = (const float*)d_in[3];
  const float* beta   = (const float*)d_in[4];
  const float* W2     = (const float*)d_in[5];
  const float* b2     = (const float*)d_in[6];
  const float* cent   = (const float*)d_in[7];

  char* ws = (char*)d_ws;   // requires ws_size >= ~36.3 MiB
  _Float16* tf = (_Float16*)(ws + WS_TF);
  _Float16* w1 = (_Float16*)(ws + WS_W1);
  _Float16* w2 = (_Float16*)(ws + WS_W2);
  float* cnorm = (float*)(ws + WS_CN);
  float* bc    = (float*)(ws + WS_BC);
  float* accum = (float*)(ws + WS_ACC);
  float* wcp   = (float*)(ws + WS_WCP);
  float* out = (float*)d_out;

  prep_all<<<2560, 256, 0, stream>>>(t_feat, W1, W2, cent, tf, w1, w2, wcp);
  prep_fin<<<64, 256, 0, stream>>>(wcp, b2, cent, w2, cnorm, bc, accum);
  router_main<<<4096, 256, 0, stream>>>((const half8*)tf, (const half8*)w1, (const half8*)w2,
                                        b1, gamma, beta, b2, bc, cnorm, accum);
  finalize_k<<<1, 64, 0, stream>>>(accum, out);
}

// Round 5
// 317.717 us; speedup vs baseline: 1.0360x; 1.0360x over previous
//
#include <hip/hip_runtime.h>
#include <math.h>

// ---------------- problem constants ----------------
#define TASKS 64
#define NB    4096
#define TDI   512     // token dim (K of GEMM1)
#define HDI   256     // hidden dim
#define VDI   484     // visual dim (padded to 512; row 484 = wc = W2^T.c fused dot column)

// ---------------- ws layout (bytes): frag-order (pre-swizzled) fp16 arrays ----------------
// tf : [64 rb][16 ks][4 rt][4 q][16 l15][8h]  f16  (4 MB)   unit strides: l15=1,q=16,rt=64,ks=256,rb=4096
// w1 : [64 t][4 w][16 ks][4 ct][4 q][16 l15][8h]   (16 MB)  strides: q=16,ct=64,ks=256,w=4096,t=16384
// w2 : [64 t][2 p][4 w][8 ks][4 ct][4 q][16 l15][8h] (16MB)  strides: q=16,ct=64,ks=256,w=2048,p=8192,t=16384
#define WS_TF   ((size_t)0)
#define WS_W1   ((size_t)4194304)
#define WS_W2   ((size_t)20971520)
#define WS_CN   ((size_t)37748736)                // 64 f32 centroid norms
#define WS_BC   ((size_t)37748992)                // 64 f32 b2.c
#define WS_ACC  ((size_t)37749248)                // 64 f32 distance accumulators
#define WS_WCP  ((size_t)37749504)                // [4 q][64 t][256 h] f32 wc partials (256 KB)

// ---------------- LDS layout (bytes): 37376 total ----------------
// HP: [8 ks][4 rt][4 q][16 l15][8h] f16 = 32768  (frag-order for GEMM2 A)
#define LDS_HP 0
#define LDS_B2 32768      // 512 f32: b2 (col 484 = b2.c, 485.. = 0)
#define LDS_R0 34816      // 256 f32: [4w][64m]
#define LDS_R1 35840      // 256 f32
#define LDS_MU 36864      // 64 f32
#define LDS_RS 37120      // 64 f32
#define SMEM_BYTES 37376

typedef _Float16 half8 __attribute__((ext_vector_type(8)));
typedef float    f32x4 __attribute__((ext_vector_type(4)));

#define MFMA16(a, b, c) __builtin_amdgcn_mfma_f32_16x16x32_f16((a), (b), (c), 0, 0, 0)

// Exact-GELU via Abramowitz-Stegun 7.1.26 erf (|err| <= 1.5e-7), ~14 VALU ops, branch-free.
__device__ __forceinline__ float gelu_exact(float x) {
  float az = fabsf(x) * 0.70710678118654752f;          // |x|/sqrt(2)
  float d  = fmaf(0.3275911f, az, 1.0f);
  float t; asm("v_rcp_f32 %0, %1" : "=v"(t) : "v"(d));
  float p  = fmaf(t, 1.061405429f, -1.453152027f);
  p = fmaf(t, p, 1.421413741f);
  p = fmaf(t, p, -0.284496736f);
  p = fmaf(t, p, 0.254829592f);
  p = p * t;
  float m = az * az * -1.4426950408889634f;            // -z^2 * log2(e)
  float e; asm("v_exp_f32 %0, %1" : "=v"(e) : "v"(m)); // 2^m = exp(-z^2)
  float er = fmaf(-p, e, 1.0f);                        // erf(|z|)
  er = copysignf(er, x);
  float hx = 0.5f * x;
  return fmaf(hx, er, hx);                             // 0.5*x*(1+erf)
}

// ================= prepass: fp32 -> frag-order fp16 via LDS tile transpose =================
// Blocks: [0,256) wc partials (4 per task, latency-parallel, FIRST so loads overlap copies)
//         [256,512) tf | [512,1536) W1 | [1536,2560) W2.
extern "C" __global__ void __launch_bounds__(256, 8)
prep_all(const float* __restrict__ t_feat,
         const float* __restrict__ W1,
         const float* __restrict__ W2,
         const float* __restrict__ cent,
         _Float16* __restrict__ tf,
         _Float16* __restrict__ w1,
         _Float16* __restrict__ w2,
         float* __restrict__ wcp) {
  __shared__ __align__(16) char pbuf[17408];           // 64 rows x 272B (128 f16 + 16B pad)
  const int bid = blockIdx.x, tid = threadIdx.x;

  if (bid < 256) {                         // wc partial: t = bid>>2, quarter q = bid&3
    int t = bid >> 2, q = bid & 3;
    int h = tid;
    int vs = q * 121;                      // 484 = 4*121
    const float* wp = W2 + ((size_t)t * VDI + vs) * HDI + h;
    const float* cp = cent + (size_t)t * VDI + vs;
    float s = 0.f;
    int v = 0;
    #pragma unroll 1
    for (; v + 8 <= 121; v += 8) {         // 8 loads in flight per round
      float x0 = wp[0 * 256], x1 = wp[1 * 256], x2 = wp[2 * 256], x3 = wp[3 * 256];
      float x4 = wp[4 * 256], x5 = wp[5 * 256], x6 = wp[6 * 256], x7 = wp[7 * 256];
      s = fmaf(x0, cp[v + 0], s); s = fmaf(x1, cp[v + 1], s);
      s = fmaf(x2, cp[v + 2], s); s = fmaf(x3, cp[v + 3], s);
      s = fmaf(x4, cp[v + 4], s); s = fmaf(x5, cp[v + 5], s);
      s = fmaf(x6, cp[v + 6], s); s = fmaf(x7, cp[v + 7], s);
      wp += 8 * 256;
    }
    s = fmaf(wp[0], cp[v], s);             // tail (121 = 15*8 + 1)
    wcp[((size_t)q * 64 + t) * 256 + h] = s;
    return;
  }

  const float* src;        // f32 base (pre-offset by kq*128 within row)
  half8* dst;              // output chunk base (1024 contiguous 16B units)
  int w2vdBase = -1;       // >=0: W2 tile, rows vd = w2vdBase + row_local

  if (bid < 512) {                         // tf: rb, kq
    int g = bid - 256;
    int rb = g >> 2, kq = g & 3;
    src = t_feat + (size_t)rb * 64 * 512 + kq * 128;
    dst = (half8*)tf + ((size_t)rb * 4096 + kq * 1024);
  } else if (bid < 1536) {                 // W1
    int g = bid - 512;
    int t = g >> 4, w_ = (g >> 2) & 3, kq = g & 3;
    src = W1 + ((size_t)t * 256 + w_ * 64) * 512 + kq * 128;
    dst = (half8*)w1 + ((size_t)t * 16384 + w_ * 4096 + kq * 1024);
  } else {                                 // W2
    int g = bid - 1536;
    int t = g >> 4, sub = g & 15;
    int p = sub >> 3, w_ = (sub >> 1) & 3, kq = sub & 1;
    src = W2 + (size_t)t * 484 * 256 + kq * 128;
    w2vdBase = p * 256 + w_ * 64;
    dst = (half8*)w2 + ((size_t)t * 16384 + p * 8192 + w_ * 2048 + kq * 1024);
  }

  // ---- stage 1: coalesced f32 read -> f16 LDS tile ----
  const int srcStride = (w2vdBase < 0) ? 512 : 256;    // tf/W1 rows 512 f32, W2 rows 256
  ushort* lds = (ushort*)pbuf;
  #pragma unroll
  for (int j = 0; j < 8; ++j) {
    int f = j * 256 + tid;                 // float4 index in [0, 2048)
    int row = f >> 5, kc = f & 31;         // 32 float4 per row
    float4 v0 = make_float4(0.f, 0.f, 0.f, 0.f);
    if (w2vdBase < 0) {
      v0 = ((const float4*)(src + (size_t)row * srcStride))[kc];
    } else {
      int vd = w2vdBase + row;
      if (vd < VDI) v0 = ((const float4*)(src + (size_t)vd * 256))[kc];
    }
    _Float16 h4[4] = {(_Float16)v0.x, (_Float16)v0.y, (_Float16)v0.z, (_Float16)v0.w};
    *(ushort4*)(&lds[row * 136 + kc * 4]) = *(const ushort4*)h4;
  }
  __syncthreads();

  // ---- stage 2: LDS -> output-linear units, fully coalesced 16B stores ----
  // (row 484 = wc gets zeros here; prep_fin overwrites it afterwards)
  #pragma unroll
  for (int j = 0; j < 4; ++j) {
    int u = j * 256 + tid;                 // unit index in [0, 1024)
    int ksl = u >> 8, rg = (u >> 6) & 3, q = (u >> 4) & 3, l15 = u & 15;
    int row = rg * 16 + l15, k8l = ksl * 4 + q;
    dst[u] = *(const half8*)(pbuf + row * 272 + k8l * 16);
  }
}

// ===== prep_fin: sum wc partials -> f16 row 484; cnorm, b2.c, accum=0 (64 blocks) =====
extern "C" __global__ void prep_fin(const float* __restrict__ wcp,
                                    const float* __restrict__ b2,
                                    const float* __restrict__ cent,
                                    _Float16* __restrict__ w2,
                                    float* __restrict__ cnorm,
                                    float* __restrict__ bc,
                                    float* __restrict__ accum) {
  __shared__ float redc[256], redb[256];
  const int t = blockIdx.x, h = threadIdx.x;
  float wc = wcp[((size_t)0 * 64 + t) * 256 + h] + wcp[((size_t)1 * 64 + t) * 256 + h]
           + wcp[((size_t)2 * 64 + t) * 256 + h] + wcp[((size_t)3 * 64 + t) * 256 + h];
  // vd=484 -> p=1, w=3, ct=2, l15=4 ; ks = h>>5, q=(h>>3)&3, within-unit h&7
  int ks = h >> 5, q = (h >> 3) & 3;
  size_t o = (size_t)t * 16384 + 8192 + 3 * 2048 + ks * 256 + 2 * 64 + q * 16 + 4;
  w2[o * 8 + (h & 7)] = (_Float16)wc;

  float c2 = 0.f, b2c = 0.f;
  for (int v = h; v < VDI; v += 256) {
    float c = cent[(size_t)t * VDI + v];
    c2 += c * c;
    b2c += b2[(size_t)t * VDI + v] * c;
  }
  redc[h] = c2; redb[h] = b2c;
  __syncthreads();
  if (h < 64) {
    c2  = redc[h] + redc[h + 64] + redc[h + 128] + redc[h + 192];
    b2c = redb[h] + redb[h + 64] + redb[h + 128] + redb[h + 192];
    #pragma unroll
    for (int off = 32; off; off >>= 1) { c2 += __shfl_xor(c2, off); b2c += __shfl_xor(b2c, off); }
    if (h == 0) { cnorm[t] = sqrtf(c2); bc[t] = b2c; accum[t] = 0.f; }
  }
}

// ============ fused main: 256 thr / 4 waves / 64x64 per wave, 4 blocks/CU ============
// Spill-free phases; all per-task vector loads in barrier shadows. RULE (R4 lesson):
// at launch_bounds(256,4) every phase sits ~4 regs under the 128 cap -> nothing may be
// held live across a phase boundary (cross-phase B prefetch cost 70us in spills).
// s_setprio(1) around MFMA clusters (4 de-phased blocks/CU -> role diversity).

#define STEP_RELOAD(A, ACC, PB) do {                                           \
  __builtin_amdgcn_s_setprio(1);                                               \
  _Pragma("unroll") for (int ct_ = 0; ct_ < 4; ++ct_) {                        \
    ACC[0][ct_] = MFMA16(A[0], b[ct_], ACC[0][ct_]);                           \
    ACC[1][ct_] = MFMA16(A[1], b[ct_], ACC[1][ct_]);                           \
    ACC[2][ct_] = MFMA16(A[2], b[ct_], ACC[2][ct_]);                           \
    ACC[3][ct_] = MFMA16(A[3], b[ct_], ACC[3][ct_]);                           \
    b[ct_] = (PB)[ct_ * 64];                                                   \
  }                                                                            \
  __builtin_amdgcn_s_setprio(0);                                               \
} while (0)

#define STEP_LAST(A, ACC) do {                                                 \
  __builtin_amdgcn_s_setprio(1);                                               \
  _Pragma("unroll") for (int ct_ = 0; ct_ < 4; ++ct_) {                        \
    ACC[0][ct_] = MFMA16(A[0], b[ct_], ACC[0][ct_]);                           \
    ACC[1][ct_] = MFMA16(A[1], b[ct_], ACC[1][ct_]);                           \
    ACC[2][ct_] = MFMA16(A[2], b[ct_], ACC[2][ct_]);                           \
    ACC[3][ct_] = MFMA16(A[3], b[ct_], ACC[3][ct_]);                           \
  }                                                                            \
  __builtin_amdgcn_s_setprio(0);                                               \
} while (0)

#define LD_A4(D, P) do { D[0] = (P)[0]; D[1] = (P)[64]; D[2] = (P)[128]; D[3] = (P)[192]; } while (0)

// Phase-3 step: 16 MFMA; B (global) reloaded per-ct (12-MFMA gap); A (LDS) single-buffered,
// reloaded interleaved with the ct=3 MFMAs.
#define P3_STEP(ACC, HN) do {                                                  \
  __builtin_amdgcn_s_setprio(1);                                               \
  ACC[0][0]=MFMA16(a0[0],b[0],ACC[0][0]); ACC[1][0]=MFMA16(a0[1],b[0],ACC[1][0]); \
  ACC[2][0]=MFMA16(a0[2],b[0],ACC[2][0]); ACC[3][0]=MFMA16(a0[3],b[0],ACC[3][0]); \
  b[0]=pc[0];                                                                  \
  ACC[0][1]=MFMA16(a0[0],b[1],ACC[0][1]); ACC[1][1]=MFMA16(a0[1],b[1],ACC[1][1]); \
  ACC[2][1]=MFMA16(a0[2],b[1],ACC[2][1]); ACC[3][1]=MFMA16(a0[3],b[1],ACC[3][1]); \
  b[1]=pc[64];                                                                 \
  ACC[0][2]=MFMA16(a0[0],b[2],ACC[0][2]); ACC[1][2]=MFMA16(a0[1],b[2],ACC[1][2]); \
  ACC[2][2]=MFMA16(a0[2],b[2],ACC[2][2]); ACC[3][2]=MFMA16(a0[3],b[2],ACC[3][2]); \
  b[2]=pc[128];                                                                \
  ACC[0][3]=MFMA16(a0[0],b[3],ACC[0][3]); a0[0]=*(const half8*)(HN);           \
  ACC[1][3]=MFMA16(a0[1],b[3],ACC[1][3]); a0[1]=*(const half8*)((HN)+1024);    \
  ACC[2][3]=MFMA16(a0[2],b[3],ACC[2][3]); a0[2]=*(const half8*)((HN)+2048);    \
  ACC[3][3]=MFMA16(a0[3],b[3],ACC[3][3]); a0[3]=*(const half8*)((HN)+3072);    \
  b[3]=pc[192]; pc+=256;                                                       \
  __builtin_amdgcn_s_setprio(0);                                               \
} while (0)

extern "C" __global__ void __launch_bounds__(256, 4)
router_main(const half8* __restrict__ tfv,
            const half8* __restrict__ w1v,
            const half8* __restrict__ w2v,
            const float* __restrict__ b1,
            const float* __restrict__ gamma,
            const float* __restrict__ beta,
            const float* __restrict__ b2,
            const float* __restrict__ bc,
            const float* __restrict__ cnorm,
            float* __restrict__ accum) {
  __shared__ __align__(16) char smem[SMEM_BYTES];

  const int tid = threadIdx.x;
  const int bx  = blockIdx.x;
  // XCD swizzle: each XCD (bx&7) works one task at a time -> task weights L2-resident.
  const int t  = ((bx & 7) << 3) | (bx >> 9);
  const int rb = (bx >> 3) & 63;

  const int lane = tid & 63;
  const int w    = tid >> 6;       // wave id 0..3
  const int quad = lane >> 4;
  const int l15  = lane & 15;

  f32x4 zero4 = {0.f, 0.f, 0.f, 0.f};
  f32x4 acc[4][4];
  #pragma unroll
  for (int rt = 0; rt < 4; ++rt)
    #pragma unroll
    for (int ct = 0; ct < 4; ++ct) acc[rt][ct] = zero4;

  half8 a0[4], a1[4], b[4];

  // ================= Phase 1: GEMM1 (K=512), barrier-free, frags direct from L2 =================
  {
    const half8* pa = tfv + ((size_t)rb * 4096 + quad * 16 + l15);
    const half8* pb = w1v + ((size_t)t * 16384 + w * 4096 + quad * 16 + l15);
    LD_A4(a0, pa);                                     // ks0
    b[0] = pb[0]; b[1] = pb[64]; b[2] = pb[128]; b[3] = pb[192];   // ks0
    a1[0] = pa[256]; a1[1] = pa[320]; a1[2] = pa[384]; a1[3] = pa[448]; // ks1
    pa += 512;            // next A load = ks2
    pb += 256;            // next B load = ks1
    #pragma unroll 1
    for (int ks = 0; ks < 14; ks += 2) {
      STEP_RELOAD(a0, acc, pb); pb += 256;   // uses ks, b <- ks+1
      LD_A4(a0, pa);            pa += 256;   // a0 <- ks+2
      STEP_RELOAD(a1, acc, pb); pb += 256;   // uses ks+1, b <- ks+2
      LD_A4(a1, pa);            pa += 256;   // a1 <- ks+3
    }
    STEP_RELOAD(a0, acc, pb);                // ks14, b <- ks15
    STEP_LAST(a1, acc);                      // ks15
  }

  // ================= Phase 2: +b1, LayerNorm, exact GELU -> H' (frag-order f16) in LDS =================
  float b1v[4];
  #pragma unroll
  for (int ct = 0; ct < 4; ++ct)
    b1v[ct] = b1[t * HDI + w * 64 + ct * 16 + l15];
  {
    float* red0 = (float*)(smem + LDS_R0);
    float* red1 = (float*)(smem + LDS_R1);
    #pragma unroll
    for (int rt = 0; rt < 4; ++rt)
      #pragma unroll
      for (int r = 0; r < 4; ++r) {
        float sv = 0.f, qv = 0.f;
        #pragma unroll
        for (int ct = 0; ct < 4; ++ct) {
          float v = acc[rt][ct][r] + b1v[ct];
          acc[rt][ct][r] = v;
          sv += v; qv += v * v;
        }
        sv += __shfl_xor(sv, 1); qv += __shfl_xor(qv, 1);
        sv += __shfl_xor(sv, 2); qv += __shfl_xor(qv, 2);
        sv += __shfl_xor(sv, 4); qv += __shfl_xor(qv, 4);
        sv += __shfl_xor(sv, 8); qv += __shfl_xor(qv, 8);
        if (l15 == 0) {
          int m = rt * 16 + quad * 4 + r;
          red0[w * 64 + m] = sv;
          red1[w * 64 + m] = qv;
        }
      }
    __syncthreads();
    if (tid < 64) {
      float s = red0[tid] + red0[64 + tid] + red0[128 + tid] + red0[192 + tid];
      float q = red1[tid] + red1[64 + tid] + red1[128 + tid] + red1[192 + tid];
      float mu = s * (1.f / HDI);
      float var = q * (1.f / HDI) - mu * mu;
      ((float*)(smem + LDS_MU))[tid] = mu;
      ((float*)(smem + LDS_RS))[tid] = rsqrtf(var + 1e-5f);
    }
    // barrier-shadow loads: gamma/beta + b2 LDS staging overlap the stats barrier
    float gvv[4], bevv[4];
    #pragma unroll
    for (int ct = 0; ct < 4; ++ct) {
      gvv[ct]  = gamma[t * HDI + w * 64 + ct * 16 + l15];
      bevv[ct] = beta [t * HDI + w * 64 + ct * 16 + l15];
    }
    {
      float* b2s = (float*)(smem + LDS_B2);
      int i0 = tid;
      b2s[i0] = (i0 < VDI) ? b2[(size_t)t * VDI + i0] : 0.f;
      int i1 = tid + 256;
      float v = 0.f;
      if (i1 < VDI) v = b2[(size_t)t * VDI + i1];
      else if (i1 == VDI) v = bc[t];
      b2s[i1] = v;
    }
    __syncthreads();
    const float* mus = (const float*)(smem + LDS_MU);
    const float* rss = (const float*)(smem + LDS_RS);
    #pragma unroll
    for (int rt = 0; rt < 4; ++rt) {
      float m4[4], s4[4];
      #pragma unroll
      for (int r = 0; r < 4; ++r) {
        int m = rt * 16 + quad * 4 + r;
        m4[r] = mus[m]; s4[r] = rss[m];
      }
      #pragma unroll
      for (int ct = 0; ct < 4; ++ct) {
        int col = w * 64 + ct * 16 + l15;
        // HP[ks2][rt][quad2][m&15][col&7]: ks2=col>>5, quad2=(col>>3)&3, m&15=quad*4+r
        int base = (((col >> 5) * 4 + rt) * 4 + ((col >> 3) & 3)) * 256
                 + quad * 64 + (l15 & 7) * 2;
        #pragma unroll
        for (int r = 0; r < 4; ++r) {
          float x = (acc[rt][ct][r] - m4[r]) * s4[r];
          x = x * gvv[ct] + bevv[ct];
          *(_Float16*)(smem + LDS_HP + base + r * 16) = (_Float16)gelu_exact(x);
        }
      }
    }
    __syncthreads();
  }

  // ================= Phase 3: GEMM2 (2 N-passes of 256, incl. fused wc dot column) =================
  {
    const float* b2s = (const float*)(smem + LDS_B2);
    float* red0 = (float*)(smem + LDS_R0);
    float* red1 = (float*)(smem + LDS_R1);
    const char* ha = smem + LDS_HP + quad * 256 + l15 * 16;

    #pragma unroll 1
    for (int pass = 0; pass < 2; ++pass) {
      const half8* pc = w2v + ((size_t)t * 16384 + pass * 8192 + w * 2048 + quad * 16 + l15);
      f32x4 acc2[4][4];
      #pragma unroll
      for (int rt = 0; rt < 4; ++rt)
        #pragma unroll
        for (int ct = 0; ct < 4; ++ct) acc2[rt][ct] = zero4;

      a0[0] = *(const half8*)(ha);        a0[1] = *(const half8*)(ha + 1024);
      a0[2] = *(const half8*)(ha + 2048); a0[3] = *(const half8*)(ha + 3072);
      b[0] = pc[0]; b[1] = pc[64]; b[2] = pc[128]; b[3] = pc[192];
      pc += 256;
      #pragma unroll 1
      for (int ks = 0; ks < 7; ++ks) {
        P3_STEP(acc2, ha + (ks + 1) * 4096);
      }
      STEP_LAST(a0, acc2);                 // ks7

      // epilogue: per-row |v|^2 (cols<484) and dot (col 484 = wc column + b2.c)
      #pragma unroll
      for (int rt = 0; rt < 4; ++rt)
        #pragma unroll
        for (int r = 0; r < 4; ++r) {
          float ssq = 0.f, dtv = 0.f;
          #pragma unroll
          for (int ct = 0; ct < 4; ++ct) {
            int vcol = pass * 256 + w * 64 + ct * 16 + l15;
            float val = acc2[rt][ct][r] + b2s[vcol];
            ssq += (vcol < VDI) ? val * val : 0.f;
            dtv += (vcol == VDI) ? val : 0.f;
          }
          ssq += __shfl_xor(ssq, 1); dtv += __shfl_xor(dtv, 1);
          ssq += __shfl_xor(ssq, 2); dtv += __shfl_xor(dtv, 2);
          ssq += __shfl_xor(ssq, 4); dtv += __shfl_xor(dtv, 4);
          ssq += __shfl_xor(ssq, 8); dtv += __shfl_xor(dtv, 8);
          if (l15 == 0) {
            int m = rt * 16 + quad * 4 + r;
            if (pass == 0) {
              red0[w * 64 + m] = ssq;
            } else {
              red0[w * 64 + m] += ssq;
              red1[w * 64 + m] = dtv;
            }
          }
        }
    }

    __syncthreads();
    if (tid < 64) {
      float ss  = red0[tid] + red0[64 + tid] + red0[128 + tid] + red0[192 + tid];
      float dot = red1[tid] + red1[64 + tid] + red1[128 + tid] + red1[192 + tid];
      float cn = fmaxf(cnorm[t], 1e-8f);
      float vn = fmaxf(sqrtf(ss), 1e-8f);
      float part = 1.0f - dot / (vn * cn);
      part += __shfl_down(part, 32);
      part += __shfl_down(part, 16);
      part += __shfl_down(part, 8);
      part += __shfl_down(part, 4);
      part += __shfl_down(part, 2);
      part += __shfl_down(part, 1);
      if (tid == 0) atomicAdd(accum + t, part);
    }
  }
}

// ================= finalize: mean, argmin =================
extern "C" __global__ void finalize_k(const float* __restrict__ accum, float* __restrict__ out) {
  int t = threadIdx.x;                               // <<<1, 64>>>
  float d = accum[t] * (1.0f / (float)NB);
  out[t] = d;
  float bd = d; int bi = t;
  #pragma unroll
  for (int off = 32; off; off >>= 1) {
    float od = __shfl_xor(bd, off);
    int   oi = __shfl_xor(bi, off);
    if (od < bd || (od == bd && oi < bi)) { bd = od; bi = oi; }   // first-min tie-break
  }
  if (t == 0) out[64] = (float)bi;
}

extern "C" void kernel_launch(void* const* d_in, const int* in_sizes, int n_in,
                              void* d_out, int out_size, void* d_ws, size_t ws_size,
                              hipStream_t stream) {
  const float* t_feat = (const float*)d_in[0];
  const float* W1     = (const float*)d_in[1];
  const float* b1     = (const float*)d_in[2];
  const float* gamma  = (const float*)d_in[3];
  const float* beta   = (const float*)d_in[4];
  const float* W2     = (const float*)d_in[5];
  const float* b2     = (const float*)d_in[6];
  const float* cent   = (const float*)d_in[7];

  char* ws = (char*)d_ws;   // requires ws_size >= ~36.3 MiB
  _Float16* tf = (_Float16*)(ws + WS_TF);
  _Float16* w1 = (_Float16*)(ws + WS_W1);
  _Float16* w2 = (_Float16*)(ws + WS_W2);
  float* cnorm = (float*)(ws + WS_CN);
  float* bc    = (float*)(ws + WS_BC);
  float* accum = (float*)(ws + WS_ACC);
  float* wcp   = (float*)(ws + WS_WCP);
  float* out = (float*)d_out;

  prep_all<<<2560, 256, 0, stream>>>(t_feat, W1, W2, cent, tf, w1, w2, wcp);
  prep_fin<<<64, 256, 0, stream>>>(wcp, b2, cent, w2, cnorm, bc, accum);
  router_main<<<4096, 256, 0, stream>>>((const half8*)tf, (const half8*)w1, (const half8*)w2,
                                        b1, gamma, beta, b2, bc, cnorm, accum);
  finalize_k<<<1, 64, 0, stream>>>(accum, out);
}

// Round 6
// 316.036 us; speedup vs baseline: 1.0415x; 1.0053x over previous
//
#include <hip/hip_runtime.h>
#include <math.h>

// ---------------- problem constants ----------------
#define TASKS 64
#define NB    4096
#define TDI   512     // token dim (K of GEMM1)
#define HDI   256     // hidden dim
#define VDI   484     // visual dim (padded to 512; row 484 = wc = W2^T.c fused dot column)

// ---------------- ws layout (bytes): frag-order (pre-swizzled) fp16 arrays ----------------
// tf : [64 rb][16 ks][4 rt][4 q][16 l15][8h]  f16  (4 MB)   unit strides: l15=1,q=16,rt=64,ks=256,rb=4096
// w1 : [64 t][4 w][16 ks][4 ct][4 q][16 l15][8h]   (16 MB)  strides: q=16,ct=64,ks=256,w=4096,t=16384
// w2 : [64 t][2 p][4 w][8 ks][4 ct][4 q][16 l15][8h] (16MB)  strides: q=16,ct=64,ks=256,w=2048,p=8192,t=16384
#define WS_TF   ((size_t)0)
#define WS_W1   ((size_t)4194304)
#define WS_W2   ((size_t)20971520)
#define WS_CN   ((size_t)37748736)                // 64 f32 centroid norms
#define WS_BC   ((size_t)37748992)                // 64 f32 b2.c
#define WS_ACC  ((size_t)37749248)                // 64 f32 distance accumulators
#define WS_WCP  ((size_t)37749504)                // [4 q][64 t][256 h] f32 wc partials (256 KB)

// ---------------- LDS layout (bytes): 37376 total ----------------
// HP: 32768 B. Phase 1: two 16 KB A-quarter buffers (global_load_lds staged).
//     Phase 2/3: H' [8 ks][4 rt][4 q][16 l15][8h] f16 (frag-order for GEMM2 A).
#define LDS_HP 0
#define LDS_B2 32768      // 512 f32: b2 (col 484 = b2.c, 485.. = 0)
#define LDS_R0 34816      // 256 f32: [4w][64m]
#define LDS_R1 35840      // 256 f32
#define LDS_MU 36864      // 64 f32
#define LDS_RS 37120      // 64 f32
#define SMEM_BYTES 37376

typedef _Float16 half8 __attribute__((ext_vector_type(8)));
typedef float    f32x4 __attribute__((ext_vector_type(4)));

#define MFMA16(a, b, c) __builtin_amdgcn_mfma_f32_16x16x32_f16((a), (b), (c), 0, 0, 0)

// async global->LDS, 16B per lane: dest = wave-uniform base + lane*16
__device__ __forceinline__ void gld_lds16(const void* g, void* l) {
  __builtin_amdgcn_global_load_lds((const __attribute__((address_space(1))) void*)g,
                                   (__attribute__((address_space(3))) void*)l, 16, 0, 0);
}

// Exact-GELU via Abramowitz-Stegun 7.1.26 erf (|err| <= 1.5e-7), ~14 VALU ops, branch-free.
__device__ __forceinline__ float gelu_exact(float x) {
  float az = fabsf(x) * 0.70710678118654752f;          // |x|/sqrt(2)
  float d  = fmaf(0.3275911f, az, 1.0f);
  float t; asm("v_rcp_f32 %0, %1" : "=v"(t) : "v"(d));
  float p  = fmaf(t, 1.061405429f, -1.453152027f);
  p = fmaf(t, p, 1.421413741f);
  p = fmaf(t, p, -0.284496736f);
  p = fmaf(t, p, 0.254829592f);
  p = p * t;
  float m = az * az * -1.4426950408889634f;            // -z^2 * log2(e)
  float e; asm("v_exp_f32 %0, %1" : "=v"(e) : "v"(m)); // 2^m = exp(-z^2)
  float er = fmaf(-p, e, 1.0f);                        // erf(|z|)
  er = copysignf(er, x);
  float hx = 0.5f * x;
  return fmaf(hx, er, hx);                             // 0.5*x*(1+erf)
}

// ================= prepass: fp32 -> frag-order fp16 via LDS tile transpose =================
// Blocks: [0,256) wc partials (4 per task, latency-parallel, FIRST so loads overlap copies)
//         [256,512) tf | [512,1536) W1 | [1536,2560) W2.
extern "C" __global__ void __launch_bounds__(256, 8)
prep_all(const float* __restrict__ t_feat,
         const float* __restrict__ W1,
         const float* __restrict__ W2,
         const float* __restrict__ cent,
         _Float16* __restrict__ tf,
         _Float16* __restrict__ w1,
         _Float16* __restrict__ w2,
         float* __restrict__ wcp) {
  __shared__ __align__(16) char pbuf[17408];           // 64 rows x 272B (128 f16 + 16B pad)
  const int bid = blockIdx.x, tid = threadIdx.x;

  if (bid < 256) {                         // wc partial: t = bid>>2, quarter q = bid&3
    int t = bid >> 2, q = bid & 3;
    int h = tid;
    int vs = q * 121;                      // 484 = 4*121
    const float* wp = W2 + ((size_t)t * VDI + vs) * HDI + h;
    const float* cp = cent + (size_t)t * VDI + vs;
    float s = 0.f;
    int v = 0;
    #pragma unroll 1
    for (; v + 8 <= 121; v += 8) {         // 8 loads in flight per round
      float x0 = wp[0 * 256], x1 = wp[1 * 256], x2 = wp[2 * 256], x3 = wp[3 * 256];
      float x4 = wp[4 * 256], x5 = wp[5 * 256], x6 = wp[6 * 256], x7 = wp[7 * 256];
      s = fmaf(x0, cp[v + 0], s); s = fmaf(x1, cp[v + 1], s);
      s = fmaf(x2, cp[v + 2], s); s = fmaf(x3, cp[v + 3], s);
      s = fmaf(x4, cp[v + 4], s); s = fmaf(x5, cp[v + 5], s);
      s = fmaf(x6, cp[v + 6], s); s = fmaf(x7, cp[v + 7], s);
      wp += 8 * 256;
    }
    s = fmaf(wp[0], cp[v], s);             // tail (121 = 15*8 + 1)
    wcp[((size_t)q * 64 + t) * 256 + h] = s;
    return;
  }

  const float* src;        // f32 base (pre-offset by kq*128 within row)
  half8* dst;              // output chunk base (1024 contiguous 16B units)
  int w2vdBase = -1;       // >=0: W2 tile, rows vd = w2vdBase + row_local

  if (bid < 512) {                         // tf: rb, kq
    int g = bid - 256;
    int rb = g >> 2, kq = g & 3;
    src = t_feat + (size_t)rb * 64 * 512 + kq * 128;
    dst = (half8*)tf + ((size_t)rb * 4096 + kq * 1024);
  } else if (bid < 1536) {                 // W1
    int g = bid - 512;
    int t = g >> 4, w_ = (g >> 2) & 3, kq = g & 3;
    src = W1 + ((size_t)t * 256 + w_ * 64) * 512 + kq * 128;
    dst = (half8*)w1 + ((size_t)t * 16384 + w_ * 4096 + kq * 1024);
  } else {                                 // W2
    int g = bid - 1536;
    int t = g >> 4, sub = g & 15;
    int p = sub >> 3, w_ = (sub >> 1) & 3, kq = sub & 1;
    src = W2 + (size_t)t * 484 * 256 + kq * 128;
    w2vdBase = p * 256 + w_ * 64;
    dst = (half8*)w2 + ((size_t)t * 16384 + p * 8192 + w_ * 2048 + kq * 1024);
  }

  // ---- stage 1: coalesced f32 read -> f16 LDS tile ----
  const int srcStride = (w2vdBase < 0) ? 512 : 256;    // tf/W1 rows 512 f32, W2 rows 256
  ushort* lds = (ushort*)pbuf;
  #pragma unroll
  for (int j = 0; j < 8; ++j) {
    int f = j * 256 + tid;                 // float4 index in [0, 2048)
    int row = f >> 5, kc = f & 31;         // 32 float4 per row
    float4 v0 = make_float4(0.f, 0.f, 0.f, 0.f);
    if (w2vdBase < 0) {
      v0 = ((const float4*)(src + (size_t)row * srcStride))[kc];
    } else {
      int vd = w2vdBase + row;
      if (vd < VDI) v0 = ((const float4*)(src + (size_t)vd * 256))[kc];
    }
    _Float16 h4[4] = {(_Float16)v0.x, (_Float16)v0.y, (_Float16)v0.z, (_Float16)v0.w};
    *(ushort4*)(&lds[row * 136 + kc * 4]) = *(const ushort4*)h4;
  }
  __syncthreads();

  // ---- stage 2: LDS -> output-linear units, fully coalesced 16B stores ----
  // (row 484 = wc gets zeros here; prep_fin overwrites it afterwards)
  #pragma unroll
  for (int j = 0; j < 4; ++j) {
    int u = j * 256 + tid;                 // unit index in [0, 1024)
    int ksl = u >> 8, rg = (u >> 6) & 3, q = (u >> 4) & 3, l15 = u & 15;
    int row = rg * 16 + l15, k8l = ksl * 4 + q;
    dst[u] = *(const half8*)(pbuf + row * 272 + k8l * 16);
  }
}

// ===== prep_fin: sum wc partials -> f16 row 484; cnorm, b2.c, accum=0 (64 blocks) =====
extern "C" __global__ void prep_fin(const float* __restrict__ wcp,
                                    const float* __restrict__ b2,
                                    const float* __restrict__ cent,
                                    _Float16* __restrict__ w2,
                                    float* __restrict__ cnorm,
                                    float* __restrict__ bc,
                                    float* __restrict__ accum) {
  __shared__ float redc[256], redb[256];
  const int t = blockIdx.x, h = threadIdx.x;
  float wc = wcp[((size_t)0 * 64 + t) * 256 + h] + wcp[((size_t)1 * 64 + t) * 256 + h]
           + wcp[((size_t)2 * 64 + t) * 256 + h] + wcp[((size_t)3 * 64 + t) * 256 + h];
  // vd=484 -> p=1, w=3, ct=2, l15=4 ; ks = h>>5, q=(h>>3)&3, within-unit h&7
  int ks = h >> 5, q = (h >> 3) & 3;
  size_t o = (size_t)t * 16384 + 8192 + 3 * 2048 + ks * 256 + 2 * 64 + q * 16 + 4;
  w2[o * 8 + (h & 7)] = (_Float16)wc;

  float c2 = 0.f, b2c = 0.f;
  for (int v = h; v < VDI; v += 256) {
    float c = cent[(size_t)t * VDI + v];
    c2 += c * c;
    b2c += b2[(size_t)t * VDI + v] * c;
  }
  redc[h] = c2; redb[h] = b2c;
  __syncthreads();
  if (h < 64) {
    c2  = redc[h] + redc[h + 64] + redc[h + 128] + redc[h + 192];
    b2c = redb[h] + redb[h + 64] + redb[h + 128] + redb[h + 192];
    #pragma unroll
    for (int off = 32; off; off >>= 1) { c2 += __shfl_xor(c2, off); b2c += __shfl_xor(b2c, off); }
    if (h == 0) { cnorm[t] = sqrtf(c2); bc[t] = b2c; accum[t] = 0.f; }
  }
}

// ============ fused main: 256 thr / 4 waves / 64x64 per wave, 4 blocks/CU ============
// P1: A-tile staged into HP LDS (global_load_lds, quarter double-buffer) -- removes the
// 4x redundant per-wave A reads from L2 and halves P1 VMEM instruction count. A and B
// frag reads split across lgkm/vm counters for more memory-level parallelism.
// RULE (R4): nothing held live across a phase boundary (128-reg cliff).
// s_setprio(1) around MFMA clusters.

// 16 MFMA step: B (global) reloaded per-ct (12-MFMA gap); A (LDS) single-buffered,
// next-step frags reloaded interleaved with the ct=3 MFMAs.
#define STEP_AB(ACC, PBP, HN) do {                                             \
  __builtin_amdgcn_s_setprio(1);                                               \
  ACC[0][0]=MFMA16(a0[0],b[0],ACC[0][0]); ACC[1][0]=MFMA16(a0[1],b[0],ACC[1][0]); \
  ACC[2][0]=MFMA16(a0[2],b[0],ACC[2][0]); ACC[3][0]=MFMA16(a0[3],b[0],ACC[3][0]); \
  b[0]=(PBP)[0];                                                               \
  ACC[0][1]=MFMA16(a0[0],b[1],ACC[0][1]); ACC[1][1]=MFMA16(a0[1],b[1],ACC[1][1]); \
  ACC[2][1]=MFMA16(a0[2],b[1],ACC[2][1]); ACC[3][1]=MFMA16(a0[3],b[1],ACC[3][1]); \
  b[1]=(PBP)[64];                                                              \
  ACC[0][2]=MFMA16(a0[0],b[2],ACC[0][2]); ACC[1][2]=MFMA16(a0[1],b[2],ACC[1][2]); \
  ACC[2][2]=MFMA16(a0[2],b[2],ACC[2][2]); ACC[3][2]=MFMA16(a0[3],b[2],ACC[3][2]); \
  b[2]=(PBP)[128];                                                             \
  ACC[0][3]=MFMA16(a0[0],b[3],ACC[0][3]); a0[0]=*(const half8*)(HN);           \
  ACC[1][3]=MFMA16(a0[1],b[3],ACC[1][3]); a0[1]=*(const half8*)((HN)+1024);    \
  ACC[2][3]=MFMA16(a0[2],b[3],ACC[2][3]); a0[2]=*(const half8*)((HN)+2048);    \
  ACC[3][3]=MFMA16(a0[3],b[3],ACC[3][3]); a0[3]=*(const half8*)((HN)+3072);    \
  b[3]=(PBP)[192]; (PBP)+=256;                                                 \
  __builtin_amdgcn_s_setprio(0);                                               \
} while (0)

// B reload only (quarter-boundary step: next A quarter not yet visible)
#define STEP_BO(ACC, PBP) do {                                                 \
  __builtin_amdgcn_s_setprio(1);                                               \
  _Pragma("unroll") for (int ct_ = 0; ct_ < 4; ++ct_) {                        \
    ACC[0][ct_] = MFMA16(a0[0], b[ct_], ACC[0][ct_]);                          \
    ACC[1][ct_] = MFMA16(a0[1], b[ct_], ACC[1][ct_]);                          \
    ACC[2][ct_] = MFMA16(a0[2], b[ct_], ACC[2][ct_]);                          \
    ACC[3][ct_] = MFMA16(a0[3], b[ct_], ACC[3][ct_]);                          \
    b[ct_] = (PBP)[ct_ * 64];                                                  \
  }                                                                            \
  (PBP) += 256;                                                                \
  __builtin_amdgcn_s_setprio(0);                                               \
} while (0)

#define STEP_LAST(ACC) do {                                                    \
  __builtin_amdgcn_s_setprio(1);                                               \
  _Pragma("unroll") for (int ct_ = 0; ct_ < 4; ++ct_) {                        \
    ACC[0][ct_] = MFMA16(a0[0], b[ct_], ACC[0][ct_]);                          \
    ACC[1][ct_] = MFMA16(a0[1], b[ct_], ACC[1][ct_]);                          \
    ACC[2][ct_] = MFMA16(a0[2], b[ct_], ACC[2][ct_]);                          \
    ACC[3][ct_] = MFMA16(a0[3], b[ct_], ACC[3][ct_]);                          \
  }                                                                            \
  __builtin_amdgcn_s_setprio(0);                                               \
} while (0)

#define LD_A4L(D, P) do {                                                      \
  D[0] = *(const half8*)(P);        D[1] = *(const half8*)((P) + 1024);        \
  D[2] = *(const half8*)((P) + 2048); D[3] = *(const half8*)((P) + 3072); } while (0)

// stage A quarter Q (1024 x 16B units) into BUF: 4 wave-insts/wave, linear both sides
#define STAGE_A(Q, BUF) do {                                                   \
  const half8* gs_ = gA + (Q) * 1024 + tid;                                    \
  char* lb_ = (BUF) + (size_t)w * 1024;                                        \
  gld_lds16(gs_,       lb_);                                                   \
  gld_lds16(gs_ + 256, lb_ + 4096);                                            \
  gld_lds16(gs_ + 512, lb_ + 8192);                                            \
  gld_lds16(gs_ + 768, lb_ + 12288);                                           \
} while (0)

extern "C" __global__ void __launch_bounds__(256, 4)
router_main(const half8* __restrict__ tfv,
            const half8* __restrict__ w1v,
            const half8* __restrict__ w2v,
            const float* __restrict__ b1,
            const float* __restrict__ gamma,
            const float* __restrict__ beta,
            const float* __restrict__ b2,
            const float* __restrict__ bc,
            const float* __restrict__ cnorm,
            float* __restrict__ accum) {
  __shared__ __align__(16) char smem[SMEM_BYTES];

  const int tid = threadIdx.x;
  const int bx  = blockIdx.x;
  // XCD swizzle: each XCD (bx&7) works one task at a time -> task weights L2-resident.
  const int t  = ((bx & 7) << 3) | (bx >> 9);
  const int rb = (bx >> 3) & 63;

  const int lane = tid & 63;
  const int w    = tid >> 6;       // wave id 0..3
  const int quad = lane >> 4;
  const int l15  = lane & 15;

  f32x4 zero4 = {0.f, 0.f, 0.f, 0.f};
  f32x4 acc[4][4];
  #pragma unroll
  for (int rt = 0; rt < 4; ++rt)
    #pragma unroll
    for (int ct = 0; ct < 4; ++ct) acc[rt][ct] = zero4;

  half8 a0[4], b[4];

  // ===== Phase 1: GEMM1 (K=512). A staged to LDS (quarters, dbuf); B direct from L2 =====
  {
    const half8* gA = tfv + (size_t)rb * 4096;
    char* buf0 = smem + LDS_HP;
    char* buf1 = smem + LDS_HP + 16384;
    const half8* pb = w1v + ((size_t)t * 16384 + w * 4096 + quad * 16 + l15);
    const char* hav0 = buf0 + quad * 256 + l15 * 16;
    const char* hav1 = buf1 + quad * 256 + l15 * 16;

    STAGE_A(0, buf0);
    STAGE_A(1, buf1);
    b[0] = pb[0]; b[1] = pb[64]; b[2] = pb[128]; b[3] = pb[192]; pb += 256;  // ks0
    __syncthreads();                       // drains staging (vmcnt 0)

    // q0: ks 0..3 from buf0
    LD_A4L(a0, hav0);
    STEP_AB(acc, pb, hav0 + 4096);
    STEP_AB(acc, pb, hav0 + 8192);
    STEP_AB(acc, pb, hav0 + 12288);
    STEP_BO(acc, pb);                      // ks3
    __syncthreads();
    STAGE_A(2, buf0);                      // refill freed buffer during q1
    // q1: ks 4..7 from buf1
    LD_A4L(a0, hav1);
    STEP_AB(acc, pb, hav1 + 4096);
    STEP_AB(acc, pb, hav1 + 8192);
    STEP_AB(acc, pb, hav1 + 12288);
    STEP_BO(acc, pb);                      // ks7
    __syncthreads();
    STAGE_A(3, buf1);                      // refill during q2
    // q2: ks 8..11 from buf0
    LD_A4L(a0, hav0);
    STEP_AB(acc, pb, hav0 + 4096);
    STEP_AB(acc, pb, hav0 + 8192);
    STEP_AB(acc, pb, hav0 + 12288);
    STEP_BO(acc, pb);                      // ks11
    __syncthreads();
    // q3: ks 12..15 from buf1
    LD_A4L(a0, hav1);
    STEP_AB(acc, pb, hav1 + 4096);
    STEP_AB(acc, pb, hav1 + 8192);
    STEP_AB(acc, pb, hav1 + 12288);
    STEP_LAST(acc);                        // ks15 (no reloads; pb would run off t-slice)
  }

  // ===== Phase 2: +b1, LayerNorm, exact GELU -> H' (frag-order f16) in LDS =====
  float b1v[4];
  #pragma unroll
  for (int ct = 0; ct < 4; ++ct)
    b1v[ct] = b1[t * HDI + w * 64 + ct * 16 + l15];
  {
    float* red0 = (float*)(smem + LDS_R0);
    float* red1 = (float*)(smem + LDS_R1);
    #pragma unroll
    for (int rt = 0; rt < 4; ++rt)
      #pragma unroll
      for (int r = 0; r < 4; ++r) {
        float sv = 0.f, qv = 0.f;
        #pragma unroll
        for (int ct = 0; ct < 4; ++ct) {
          float v = acc[rt][ct][r] + b1v[ct];
          acc[rt][ct][r] = v;
          sv += v; qv += v * v;
        }
        sv += __shfl_xor(sv, 1); qv += __shfl_xor(qv, 1);
        sv += __shfl_xor(sv, 2); qv += __shfl_xor(qv, 2);
        sv += __shfl_xor(sv, 4); qv += __shfl_xor(qv, 4);
        sv += __shfl_xor(sv, 8); qv += __shfl_xor(qv, 8);
        if (l15 == 0) {
          int m = rt * 16 + quad * 4 + r;
          red0[w * 64 + m] = sv;
          red1[w * 64 + m] = qv;
        }
      }
    __syncthreads();
    if (tid < 64) {
      float s = red0[tid] + red0[64 + tid] + red0[128 + tid] + red0[192 + tid];
      float q = red1[tid] + red1[64 + tid] + red1[128 + tid] + red1[192 + tid];
      float mu = s * (1.f / HDI);
      float var = q * (1.f / HDI) - mu * mu;
      ((float*)(smem + LDS_MU))[tid] = mu;
      ((float*)(smem + LDS_RS))[tid] = rsqrtf(var + 1e-5f);
    }
    // barrier-shadow loads: gamma/beta + b2 LDS staging overlap the stats barrier
    float gvv[4], bevv[4];
    #pragma unroll
    for (int ct = 0; ct < 4; ++ct) {
      gvv[ct]  = gamma[t * HDI + w * 64 + ct * 16 + l15];
      bevv[ct] = beta [t * HDI + w * 64 + ct * 16 + l15];
    }
    {
      float* b2s = (float*)(smem + LDS_B2);
      int i0 = tid;
      b2s[i0] = (i0 < VDI) ? b2[(size_t)t * VDI + i0] : 0.f;
      int i1 = tid + 256;
      float v = 0.f;
      if (i1 < VDI) v = b2[(size_t)t * VDI + i1];
      else if (i1 == VDI) v = bc[t];
      b2s[i1] = v;
    }
    __syncthreads();
    const float* mus = (const float*)(smem + LDS_MU);
    const float* rss = (const float*)(smem + LDS_RS);
    #pragma unroll
    for (int rt = 0; rt < 4; ++rt) {
      float m4[4], s4[4];
      #pragma unroll
      for (int r = 0; r < 4; ++r) {
        int m = rt * 16 + quad * 4 + r;
        m4[r] = mus[m]; s4[r] = rss[m];
      }
      #pragma unroll
      for (int ct = 0; ct < 4; ++ct) {
        int col = w * 64 + ct * 16 + l15;
        // HP[ks2][rt][quad2][m&15][col&7]: ks2=col>>5, quad2=(col>>3)&3, m&15=quad*4+r
        int base = (((col >> 5) * 4 + rt) * 4 + ((col >> 3) & 3)) * 256
                 + quad * 64 + (l15 & 7) * 2;
        #pragma unroll
        for (int r = 0; r < 4; ++r) {
          float x = (acc[rt][ct][r] - m4[r]) * s4[r];
          x = x * gvv[ct] + bevv[ct];
          *(_Float16*)(smem + LDS_HP + base + r * 16) = (_Float16)gelu_exact(x);
        }
      }
    }
    __syncthreads();
  }

  // ===== Phase 3: GEMM2 (2 N-passes of 256, incl. fused wc dot column) =====
  {
    const float* b2s = (const float*)(smem + LDS_B2);
    float* red0 = (float*)(smem + LDS_R0);
    float* red1 = (float*)(smem + LDS_R1);
    const char* ha = smem + LDS_HP + quad * 256 + l15 * 16;

    #pragma unroll 1
    for (int pass = 0; pass < 2; ++pass) {
      const half8* pc = w2v + ((size_t)t * 16384 + pass * 8192 + w * 2048 + quad * 16 + l15);
      f32x4 acc2[4][4];
      #pragma unroll
      for (int rt = 0; rt < 4; ++rt)
        #pragma unroll
        for (int ct = 0; ct < 4; ++ct) acc2[rt][ct] = zero4;

      LD_A4L(a0, ha);
      b[0] = pc[0]; b[1] = pc[64]; b[2] = pc[128]; b[3] = pc[192];
      pc += 256;
      #pragma unroll 1
      for (int ks = 0; ks < 7; ++ks) {
        STEP_AB(acc2, pc, ha + (ks + 1) * 4096);
      }
      STEP_LAST(acc2);                     // ks7

      // epilogue: per-row |v|^2 (cols<484) and dot (col 484 = wc column + b2.c)
      #pragma unroll
      for (int rt = 0; rt < 4; ++rt)
        #pragma unroll
        for (int r = 0; r < 4; ++r) {
          float ssq = 0.f, dtv = 0.f;
          #pragma unroll
          for (int ct = 0; ct < 4; ++ct) {
            int vcol = pass * 256 + w * 64 + ct * 16 + l15;
            float val = acc2[rt][ct][r] + b2s[vcol];
            ssq += (vcol < VDI) ? val * val : 0.f;
            dtv += (vcol == VDI) ? val : 0.f;
          }
          ssq += __shfl_xor(ssq, 1); dtv += __shfl_xor(dtv, 1);
          ssq += __shfl_xor(ssq, 2); dtv += __shfl_xor(dtv, 2);
          ssq += __shfl_xor(ssq, 4); dtv += __shfl_xor(dtv, 4);
          ssq += __shfl_xor(ssq, 8); dtv += __shfl_xor(dtv, 8);
          if (l15 == 0) {
            int m = rt * 16 + quad * 4 + r;
            if (pass == 0) {
              red0[w * 64 + m] = ssq;
            } else {
              red0[w * 64 + m] += ssq;
              red1[w * 64 + m] = dtv;
            }
          }
        }
    }

    __syncthreads();
    if (tid < 64) {
      float ss  = red0[tid] + red0[64 + tid] + red0[128 + tid] + red0[192 + tid];
      float dot = red1[tid] + red1[64 + tid] + red1[128 + tid] + red1[192 + tid];
      float cn = fmaxf(cnorm[t], 1e-8f);
      float vn = fmaxf(sqrtf(ss), 1e-8f);
      float part = 1.0f - dot / (vn * cn);
      part += __shfl_down(part, 32);
      part += __shfl_down(part, 16);
      part += __shfl_down(part, 8);
      part += __shfl_down(part, 4);
      part += __shfl_down(part, 2);
      part += __shfl_down(part, 1);
      if (tid == 0) atomicAdd(accum + t, part);
    }
  }
}

// ================= finalize: mean, argmin =================
extern "C" __global__ void finalize_k(const float* __restrict__ accum, float* __restrict__ out) {
  int t = threadIdx.x;                               // <<<1, 64>>>
  float d = accum[t] * (1.0f / (float)NB);
  out[t] = d;
  float bd = d; int bi = t;
  #pragma unroll
  for (int off = 32; off; off >>= 1) {
    float od = __shfl_xor(bd, off);
    int   oi = __shfl_xor(bi, off);
    if (od < bd || (od == bd && oi < bi)) { bd = od; bi = oi; }   // first-min tie-break
  }
  if (t == 0) out[64] = (float)bi;
}

extern "C" void kernel_launch(void* const* d_in, const int* in_sizes, int n_in,
                              void* d_out, int out_size, void* d_ws, size_t ws_size,
                              hipStream_t stream) {
  const float* t_feat = (const float*)d_in[0];
  const float* W1     = (const float*)d_in[1];
  const float* b1     = (const float*)d_in[2];
  const float* gamma  = (const float*)d_in[3];
  const float* beta   = (const float*)d_in[4];
  const float* W2     = (const float*)d_in[5];
  const float* b2     = (const float*)d_in[6];
  const float* cent   = (const float*)d_in[7];

  char* ws = (char*)d_ws;   // requires ws_size >= ~36.3 MiB
  _Float16* tf = (_Float16*)(ws + WS_TF);
  _Float16* w1 = (_Float16*)(ws + WS_W1);
  _Float16* w2 = (_Float16*)(ws + WS_W2);
  float* cnorm = (float*)(ws + WS_CN);
  float* bc    = (float*)(ws + WS_BC);
  float* accum = (float*)(ws + WS_ACC);
  float* wcp   = (float*)(ws + WS_WCP);
  float* out = (float*)d_out;

  prep_all<<<2560, 256, 0, stream>>>(t_feat, W1, W2, cent, tf, w1, w2, wcp);
  prep_fin<<<64, 256, 0, stream>>>(wcp, b2, cent, w2, cnorm, bc, accum);
  router_main<<<4096, 256, 0, stream>>>((const half8*)tf, (const half8*)w1, (const half8*)w2,
                                        b1, gamma, beta, b2, bc, cnorm, accum);
  finalize_k<<<1, 64, 0, stream>>>(accum, out);
}